// Round 20
// baseline (875.687 us; speedup 1.0000x reference)
//
#include <hip/hip_runtime.h>

typedef unsigned short u16;
typedef __attribute__((ext_vector_type(8))) short bf16x8;
typedef __attribute__((ext_vector_type(4))) float f32x4;

#define C_    192
#define HW_   65536

__device__ inline u16 f2bf(float f) {
  union { float f; unsigned u; } x; x.f = f;
  unsigned r = x.u + 0x7FFFu + ((x.u >> 16) & 1u);
  return (u16)(r >> 16);
}
__device__ inline float bf2f(u16 s) {
  union { unsigned u; float f; } x; x.u = ((unsigned)s) << 16;
  return x.f;
}
// packed RNE f32x2 -> bf16x2 (one VALU op; no builtin on gfx950)
__device__ inline unsigned pkbf(float lo, float hi) {
  unsigned r;
  asm("v_cvt_pk_bf16_f32 %0, %1, %2" : "=v"(r) : "v"(lo), "v"(hi));
  return r;
}

// ---------------- k0: weights fp32 -> bf16, combined qkv bias ----------------
__global__ void k_convert(const float* __restrict__ qkv_w, const float* __restrict__ proj_w,
                          const float* __restrict__ q_bias, const float* __restrict__ v_bias,
                          u16* __restrict__ wq, u16* __restrict__ wp, float* __restrict__ qkvb) {
  int i = blockIdx.x * 256 + threadIdx.x;
  if (i < 110592) wq[i] = f2bf(qkv_w[i]);
  else if (i < 147456) wp[i - 110592] = f2bf(proj_w[i - 110592]);
  else if (i < 148032) {
    int j = i - 147456;
    qkvb[j] = (j < 192) ? q_bias[j] : ((j < 384) ? 0.f : v_bias[j - 384]);
  }
}

// ---------------- k1: CPB MLP table (225 x 8) ----------------
__global__ void k_table(const float* __restrict__ w1, const float* __restrict__ b1,
                        const float* __restrict__ w2, float* __restrict__ table) {
  int row = blockIdx.x;            // 0..224
  int tid = threadIdx.x;
  int a = row / 15, b = row % 15;
  float va = (float)(a - 7) * (8.0f / 7.0f);
  float vb = (float)(b - 7) * (8.0f / 7.0f);
  float c0 = copysignf(log2f(fabsf(va) + 1.0f) * (1.0f / 3.0f), va);
  float c1 = copysignf(log2f(fabsf(vb) + 1.0f) * (1.0f / 3.0f), vb);
  float acc[8];
#pragma unroll
  for (int o = 0; o < 8; ++o) acc[o] = 0.f;
  for (int k = tid; k < 512; k += 256) {
    float h = fmaxf(c0 * w1[k] + c1 * w1[512 + k] + b1[k], 0.f);
#pragma unroll
    for (int o = 0; o < 8; ++o) acc[o] += h * w2[k * 8 + o];
  }
  __shared__ float part[4][8];
  int wave = tid >> 6;
#pragma unroll
  for (int o = 0; o < 8; ++o) {
    float v = acc[o];
    v += __shfl_xor(v, 1, 64);  v += __shfl_xor(v, 2, 64);
    v += __shfl_xor(v, 4, 64);  v += __shfl_xor(v, 8, 64);
    v += __shfl_xor(v, 16, 64); v += __shfl_xor(v, 32, 64);
    acc[o] = v;
  }
  if ((tid & 63) == 0)
#pragma unroll
    for (int o = 0; o < 8; ++o) part[wave][o] = acc[o];
  __syncthreads();
  if (tid < 8)
    table[row * 8 + tid] = part[0][tid] + part[1][tid] + part[2][tid] + part[3][tid];
}

// ---- k2: bias grid, flat = h*4096 + t*64 + g*16 + nt*4 + r;
//      value = bias[h][query t][key s = nt*16 + g*4 + r] ----
__global__ void k_biasfill(const float* __restrict__ table, float* __restrict__ bias3) {
  int p = blockIdx.x * 256 + threadIdx.x;   // 32768 total
  int h = p >> 12, t = (p >> 6) & 63, g = (p >> 4) & 3, u = p & 15;
  int nt = u >> 2, r = u & 3;
  int s = nt * 16 + g * 4 + r;
  int idx = ((t >> 3) - (s >> 3) + 7) * 15 + ((t & 7) - (s & 7) + 7);
  float v = table[idx * 8 + h];
  bias3[p] = 16.0f / (1.0f + __expf(-v));
}

// ------- main fused kernel: 1 window/block, 8 waves, (512,4): 64-reg diet -------
__global__ __launch_bounds__(512, 4)
void k_main(const float* __restrict__ x,
            const float* __restrict__ ls, const float* __restrict__ proj_b,
            const u16* __restrict__ wq, const u16* __restrict__ wp,
            const float* __restrict__ qkvb, const float* __restrict__ bias3,
            float* __restrict__ out) {
  __shared__ u16 smem[39936];                 // 79,872 B -> 2 blocks/CU
  u16* R0   = smem;                           // [64][200]: x, later ao
  u16* SwKb = smem + 12800;                   // 8 x 1536: per-wave Hk (live thru attn)
  u16* SwVb = smem + 25088;                   // 8 x 1728: per-wave Hq -> Hv -> Pw
  float* ikwb = (float*)(smem + 38912);       // 8 x 64 f32

  int tid  = threadIdx.x;
  int h = tid >> 6, lane = tid & 63, g = lane >> 4, li = lane & 15;
  int tt = h & 3, half = h >> 2;              // proj roles
  int bid = blockIdx.x;                       // 4096 blocks
  int b = bid >> 10, wy = (bid >> 5) & 31, wx = bid & 31;
  const float* xb = x + (size_t)b * C_ * HW_;
  int base = (wy * 8) * 256 + wx * 8;
  bf16x8 z8 = {0, 0, 0, 0, 0, 0, 0, 0};
  f32x4 zf = {0.f, 0.f, 0.f, 0.f};

  u16* SwK = SwKb + h * 1536;
  u16* SwV = SwVb + h * 1728;
  float* ikw = ikwb + h * 64;
  float scaleh = __expf(fminf(ls[h], 4.6051702f));

  // ---- P1: stage x -> bf16 LDS [t][c] ----
#pragma unroll
  for (int it = 0; it < 6; ++it) {
    int i4 = tid + it * 512;                  // 3072 tasks
    int c = i4 >> 4, rem = i4 & 15;
    int ty = rem >> 1, jj = (rem & 1) * 4;
    float4 v = *(const float4*)(xb + c * HW_ + base + ty * 256 + jj);
    int t0 = ty * 8 + jj;
    unsigned p01 = pkbf(v.x, v.y), p23 = pkbf(v.z, v.w);
    R0[(t0 + 0) * 200 + c] = (u16)p01;
    R0[(t0 + 1) * 200 + c] = (u16)(p01 >> 16);
    R0[(t0 + 2) * 200 + c] = (u16)p23;
    R0[(t0 + 3) * 200 + c] = (u16)(p23 >> 16);
  }
  __syncthreads();                            // B1

  float iqr[4];
  bf16x8 qf[4];

  // ---- q GEMM (weights reloaded per tb; laundered to block LICM) -> Hq(SwV) ----
  {
    uintptr_t p0 = (uintptr_t)(wq + (size_t)(h * 24 + li) * 192 + g * 8);
    uintptr_t p1 = (uintptr_t)(wq + (size_t)(h * 24 + 16 + (li & 7)) * 192 + g * 8);
    f32x4 cb0 = *(const f32x4*)(qkvb + h * 24 + g * 4);
    f32x4 cb1 = *(const f32x4*)(qkvb + h * 24 + 16 + g * 4);   // g>=2 junk, masked
#pragma unroll
    for (int tb = 0; tb < 4; ++tb) {
      asm volatile("" : "+v"(p0), "+v"(p1));
      int t = tb * 16 + li;
      bf16x8 xf[6];
#pragma unroll
      for (int ks = 0; ks < 6; ++ks)
        xf[ks] = *(const bf16x8*)&R0[t * 200 + ks * 32 + g * 8];
      f32x4 a0 = zf, a1 = zf;
      __builtin_amdgcn_s_setprio(1);
#pragma unroll
      for (int ks = 0; ks < 6; ++ks) {
        bf16x8 w0 = *(const bf16x8*)((const u16*)p0 + ks * 32);
        bf16x8 w1 = *(const bf16x8*)((const u16*)p1 + ks * 32);
        a0 = __builtin_amdgcn_mfma_f32_16x16x32_bf16(w0, xf[ks], a0, 0, 0, 0);
        a1 = __builtin_amdgcn_mfma_f32_16x16x32_bf16(w1, xf[ks], a1, 0, 0, 0);
      }
      __builtin_amdgcn_s_setprio(0);
      float p = 0.f;
#pragma unroll
      for (int r = 0; r < 4; ++r) { a0[r] += cb0[r]; p += a0[r] * a0[r]; }
      if (g < 2) {
#pragma unroll
        for (int r = 0; r < 4; ++r) { a1[r] += cb1[r]; p += a1[r] * a1[r]; }
      }
      p += __shfl_xor(p, 16, 64);
      p += __shfl_xor(p, 32, 64);
      iqr[tb] = __builtin_amdgcn_rsqf(fmaxf(p, 1e-24f)) * scaleh;
      uint2 pk;
      pk.x = pkbf(a0[0], a0[1]);
      pk.y = pkbf(a0[2], a0[3]);
      *(uint2*)&SwV[t * 24 + g * 4] = pk;
      if (g < 2) {
        pk.x = pkbf(a1[0], a1[1]);
        pk.y = pkbf(a1[2], a1[3]);
        *(uint2*)&SwV[t * 24 + 16 + g * 4] = pk;
      }
    }
  }
  // hoist q fragments (same-wave LDS, in-order); Hq dead after
#pragma unroll
  for (int tb = 0; tb < 4; ++tb)
    qf[tb] = (g < 3) ? *(const bf16x8*)&SwV[(tb * 16 + li) * 24 + g * 8] : z8;

  // ---- k GEMM -> Hk(SwK, stays live); norms -> ikw ----
  {
    uintptr_t p0 = (uintptr_t)(wq + (size_t)(192 + h * 24 + li) * 192 + g * 8);
    uintptr_t p1 = (uintptr_t)(wq + (size_t)(192 + h * 24 + 16 + (li & 7)) * 192 + g * 8);
    f32x4 cb0 = *(const f32x4*)(qkvb + 192 + h * 24 + g * 4);
    f32x4 cb1 = *(const f32x4*)(qkvb + 192 + h * 24 + 16 + g * 4);
#pragma unroll
    for (int nt = 0; nt < 4; ++nt) {
      asm volatile("" : "+v"(p0), "+v"(p1));
      int t = nt * 16 + li;
      bf16x8 xf[6];
#pragma unroll
      for (int ks = 0; ks < 6; ++ks)
        xf[ks] = *(const bf16x8*)&R0[t * 200 + ks * 32 + g * 8];
      f32x4 a0 = zf, a1 = zf;
      __builtin_amdgcn_s_setprio(1);
#pragma unroll
      for (int ks = 0; ks < 6; ++ks) {
        bf16x8 w0 = *(const bf16x8*)((const u16*)p0 + ks * 32);
        bf16x8 w1 = *(const bf16x8*)((const u16*)p1 + ks * 32);
        a0 = __builtin_amdgcn_mfma_f32_16x16x32_bf16(w0, xf[ks], a0, 0, 0, 0);
        a1 = __builtin_amdgcn_mfma_f32_16x16x32_bf16(w1, xf[ks], a1, 0, 0, 0);
      }
      __builtin_amdgcn_s_setprio(0);
      float p = 0.f;
#pragma unroll
      for (int r = 0; r < 4; ++r) { a0[r] += cb0[r]; p += a0[r] * a0[r]; }
      if (g < 2) {
#pragma unroll
        for (int r = 0; r < 4; ++r) { a1[r] += cb1[r]; p += a1[r] * a1[r]; }
      }
      p += __shfl_xor(p, 16, 64);
      p += __shfl_xor(p, 32, 64);
      float ik = __builtin_amdgcn_rsqf(fmaxf(p, 1e-24f));
      if (g == 0) ikw[t] = ik;
      uint2 pk;
      pk.x = pkbf(a0[0], a0[1]);
      pk.y = pkbf(a0[2], a0[3]);
      *(uint2*)&SwK[t * 24 + g * 4] = pk;
      if (g < 2) {
        pk.x = pkbf(a1[0], a1[1]);
        pk.y = pkbf(a1[2], a1[3]);
        *(uint2*)&SwK[t * 24 + 16 + g * 4] = pk;
      }
    }
  }

  // ---- v GEMM -> Hv(SwV, stride 72; Hq dead) ----
  {
    uintptr_t p0 = (uintptr_t)(wq + (size_t)(384 + h * 24 + li) * 192 + g * 8);
    uintptr_t p1 = (uintptr_t)(wq + (size_t)(384 + h * 24 + 16 + (li & 7)) * 192 + g * 8);
    float vb0 = qkvb[384 + h * 24 + li];
    float vb1 = qkvb[384 + h * 24 + 16 + (li & 7)];
#pragma unroll
    for (int tb = 0; tb < 4; ++tb) {
      asm volatile("" : "+v"(p0), "+v"(p1));
      int t = tb * 16 + li;
      bf16x8 xf[6];
#pragma unroll
      for (int ks = 0; ks < 6; ++ks)
        xf[ks] = *(const bf16x8*)&R0[t * 200 + ks * 32 + g * 8];
      f32x4 a0 = zf, a1 = zf;
      __builtin_amdgcn_s_setprio(1);
#pragma unroll
      for (int ks = 0; ks < 6; ++ks) {
        bf16x8 w0 = *(const bf16x8*)((const u16*)p0 + ks * 32);
        bf16x8 w1 = *(const bf16x8*)((const u16*)p1 + ks * 32);
        a0 = __builtin_amdgcn_mfma_f32_16x16x32_bf16(xf[ks], w0, a0, 0, 0, 0);
        a1 = __builtin_amdgcn_mfma_f32_16x16x32_bf16(xf[ks], w1, a1, 0, 0, 0);
      }
      __builtin_amdgcn_s_setprio(0);
      uint2 pk;
      pk.x = pkbf(a0[0] + vb0, a0[1] + vb0);
      pk.y = pkbf(a0[2] + vb0, a0[3] + vb0);
      *(uint2*)&SwV[li * 72 + tb * 16 + g * 4] = pk;
      if (li < 8) {
        pk.x = pkbf(a1[0] + vb1, a1[1] + vb1);
        pk.y = pkbf(a1[2] + vb1, a1[3] + vb1);
        *(uint2*)&SwV[(16 + li) * 72 + tb * 16 + g * 4] = pk;
      }
    }
  }
  // hoist V^T fragments; Hv dead after -> Pw reuses SwV
  bf16x8 vf0[2], vf1[2];
#pragma unroll
  for (int ks = 0; ks < 2; ++ks) {
    vf0[ks] = *(const bf16x8*)&SwV[li * 72 + ks * 32 + g * 8];
    vf1[ks] = (li < 8) ? *(const bf16x8*)&SwV[(16 + li) * 72 + ks * 32 + g * 8] : z8;
  }
  __syncthreads();                            // B2a: all x reads done before ao writes R0

  // ---- attention: kf read from SwK per nt; P bounce in SwV ----
#pragma unroll
  for (int tb = 0; tb < 4; ++tb) {
    f32x4 s4[4];
    __builtin_amdgcn_s_setprio(1);
#pragma unroll
    for (int nt = 0; nt < 4; ++nt) {
      bf16x8 kfn = (g < 3) ? *(const bf16x8*)&SwK[(nt * 16 + li) * 24 + g * 8] : z8;
      s4[nt] = __builtin_amdgcn_mfma_f32_16x16x32_bf16(kfn, qf[tb], zf, 0, 0, 0);
    }
    __builtin_amdgcn_s_setprio(0);
    float iq = iqr[tb];
    const float* bp = bias3 + ((h * 64 + tb * 16 + li) << 6) + (g << 4);
#pragma unroll
    for (int nt = 0; nt < 4; ++nt) {
      f32x4 ik4 = *(const f32x4*)&ikw[nt * 16 + g * 4];
      f32x4 bxl = *(const f32x4*)(bp + (nt << 2));
#pragma unroll
      for (int r = 0; r < 4; ++r)
        s4[nt][r] = s4[nt][r] * iq * ik4[r] + bxl[r];
    }
    float m = s4[0][0];
#pragma unroll
    for (int nt = 0; nt < 4; ++nt)
#pragma unroll
      for (int r = 0; r < 4; ++r) m = fmaxf(m, s4[nt][r]);
    m = fmaxf(m, __shfl_xor(m, 16, 64));
    m = fmaxf(m, __shfl_xor(m, 32, 64));
    float sum = 0.f;
#pragma unroll
    for (int nt = 0; nt < 4; ++nt)
#pragma unroll
      for (int r = 0; r < 4; ++r) { float e = __expf(s4[nt][r] - m); s4[nt][r] = e; sum += e; }
    sum += __shfl_xor(sum, 16, 64);
    sum += __shfl_xor(sum, 32, 64);
    float is = __builtin_amdgcn_rcpf(sum);
#pragma unroll
    for (int nt = 0; nt < 4; ++nt) {
      uint2 pk;
      pk.x = pkbf(s4[nt][0], s4[nt][1]);
      pk.y = pkbf(s4[nt][2], s4[nt][3]);
      *(uint2*)&SwV[li * 72 + nt * 16 + g * 4] = pk;
    }
    f32x4 o0 = zf, o1 = zf;
    __builtin_amdgcn_s_setprio(1);
#pragma unroll
    for (int ks = 0; ks < 2; ++ks) {
      bf16x8 pf = *(const bf16x8*)&SwV[li * 72 + ks * 32 + g * 8];
      o0 = __builtin_amdgcn_mfma_f32_16x16x32_bf16(vf0[ks], pf, o0, 0, 0, 0);
      o1 = __builtin_amdgcn_mfma_f32_16x16x32_bf16(vf1[ks], pf, o1, 0, 0, 0);
    }
    __builtin_amdgcn_s_setprio(0);
    int t = tb * 16 + li;
    {
      uint2 pk;
      pk.x = pkbf(o0[0] * is, o0[1] * is);
      pk.y = pkbf(o0[2] * is, o0[3] * is);
      *(uint2*)&R0[t * 200 + h * 24 + g * 4] = pk;
    }
    if (g < 2) {
      uint2 pk;
      pk.x = pkbf(o1[0] * is, o1[1] * is);
      pk.y = pkbf(o1[2] * is, o1[3] * is);
      *(uint2*)&R0[t * 200 + h * 24 + 16 + g * 4] = pk;
    }
  }
  __syncthreads();                            // B2 (ao complete)

  // ---- proj: af from R0; obuf [192][68] over SwK/SwV region ----
  u16* obuf = smem + 12800;
  {
    bf16x8 af[6];
#pragma unroll
    for (int ks = 0; ks < 6; ++ks)
      af[ks] = *(const bf16x8*)&R0[(tt * 16 + li) * 200 + ks * 32 + g * 8];
#pragma unroll
    for (int it = 0; it < 6; ++it) {
      int ct = half * 96 + it * 16;
      const u16* wr = wp + (size_t)(ct + li) * 192 + g * 8;
      f32x4 a0 = zf, a1 = zf;
      __builtin_amdgcn_s_setprio(1);
#pragma unroll
      for (int ks = 0; ks < 3; ++ks) {
        bf16x8 w0 = *(const bf16x8*)(wr + ks * 32);
        bf16x8 w1 = *(const bf16x8*)(wr + (ks + 3) * 32);
        a0 = __builtin_amdgcn_mfma_f32_16x16x32_bf16(af[ks], w0, a0, 0, 0, 0);
        a1 = __builtin_amdgcn_mfma_f32_16x16x32_bf16(af[ks + 3], w1, a1, 0, 0, 0);
      }
      __builtin_amdgcn_s_setprio(0);
      float pb = proj_b[ct + li];
      uint2 pk;
      pk.x = pkbf(a0[0] + a1[0] + pb, a0[1] + a1[1] + pb);
      pk.y = pkbf(a0[2] + a1[2] + pb, a0[3] + a1[3] + pb);
      *(uint2*)&obuf[(ct + li) * 68 + tt * 16 + g * 4] = pk;
    }
  }
  __syncthreads();                            // B3

  // ---- P6: residual (x re-read) + b64 obuf reads + coalesced store ----
  float* ob = out + (size_t)b * C_ * HW_;
  float4 xv[6];
#pragma unroll
  for (int it = 0; it < 6; ++it) {
    int i4 = tid + it * 512;
    int c = i4 >> 4, rem = i4 & 15;
    int ty = rem >> 1, jj = (rem & 1) * 4;
    xv[it] = *(const float4*)(xb + c * HW_ + base + ty * 256 + jj);
  }
  uint2 ov[6];
#pragma unroll
  for (int it = 0; it < 6; ++it) {
    int i4 = tid + it * 512;
    int c = i4 >> 4, rem = i4 & 15;
    int ty = rem >> 1, jj = (rem & 1) * 4;
    ov[it] = *(const uint2*)&obuf[c * 68 + ty * 8 + jj];
  }
#pragma unroll
  for (int it = 0; it < 6; ++it) {
    int i4 = tid + it * 512;
    int c = i4 >> 4, rem = i4 & 15;
    int ty = rem >> 1, jj = (rem & 1) * 4;
    float4 r;
    r.x = xv[it].x + bf2f((u16)(ov[it].x & 0xFFFFu));
    r.y = xv[it].y + bf2f((u16)(ov[it].x >> 16));
    r.z = xv[it].z + bf2f((u16)(ov[it].y & 0xFFFFu));
    r.w = xv[it].w + bf2f((u16)(ov[it].y >> 16));
    *(float4*)(ob + c * HW_ + base + ty * 256 + jj) = r;
  }
}

// ---------------- launcher ----------------
extern "C" void kernel_launch(void* const* d_in, const int* in_sizes, int n_in,
                              void* d_out, int out_size, void* d_ws, size_t ws_size,
                              hipStream_t stream) {
  const float* x      = (const float*)d_in[0];
  const float* qkv_w  = (const float*)d_in[2];
  const float* q_bias = (const float*)d_in[3];
  const float* v_bias = (const float*)d_in[4];
  const float* ls     = (const float*)d_in[5];
  const float* w1     = (const float*)d_in[6];
  const float* b1     = (const float*)d_in[7];
  const float* w2     = (const float*)d_in[8];
  const float* proj_w = (const float*)d_in[9];
  const float* proj_b = (const float*)d_in[10];

  u16*   wq    = (u16*)d_ws;                               // 110592 bf16
  u16*   wpv   = wq + 110592;                              // 36864 bf16 -> byte 294912
  float* qkvb  = (float*)((char*)d_ws + 294912);           // 576 f32   -> 297216
  float* bias3 = (float*)((char*)d_ws + 297216);           // 32768 f32 -> 428288
  float* table = (float*)((char*)d_ws + 428288);           // 1800 f32
  float* out   = (float*)d_out;

  hipLaunchKernelGGL(k_convert, dim3(579), dim3(256), 0, stream,
                     qkv_w, proj_w, q_bias, v_bias, wq, wpv, qkvb);
  hipLaunchKernelGGL(k_table, dim3(225), dim3(256), 0, stream, w1, b1, w2, table);
  hipLaunchKernelGGL(k_biasfill, dim3(128), dim3(256), 0, stream, table, bias3);
  hipLaunchKernelGGL(k_main, dim3(4096), dim3(512), 0, stream,
                     x, ls, proj_b, wq, wpv, qkvb, bias3, out);
}

// Round 21
// 409.164 us; speedup vs baseline: 2.1402x; 2.1402x over previous
//
#include <hip/hip_runtime.h>

typedef unsigned short u16;
typedef __attribute__((ext_vector_type(8))) short bf16x8;
typedef __attribute__((ext_vector_type(4))) float f32x4;

#define C_    192
#define HW_   65536

__device__ inline u16 f2bf(float f) {
  union { float f; unsigned u; } x; x.f = f;
  unsigned r = x.u + 0x7FFFu + ((x.u >> 16) & 1u);
  return (u16)(r >> 16);
}
__device__ inline float bf2f(u16 s) {
  union { unsigned u; float f; } x; x.u = ((unsigned)s) << 16;
  return x.f;
}
// packed RNE f32x2 -> bf16x2 (one VALU op; no builtin on gfx950)
__device__ inline unsigned pkbf(float lo, float hi) {
  unsigned r;
  asm("v_cvt_pk_bf16_f32 %0, %1, %2" : "=v"(r) : "v"(lo), "v"(hi));
  return r;
}

// ---------------- k0: weights fp32 -> bf16, combined qkv bias ----------------
__global__ void k_convert(const float* __restrict__ qkv_w, const float* __restrict__ proj_w,
                          const float* __restrict__ q_bias, const float* __restrict__ v_bias,
                          u16* __restrict__ wq, u16* __restrict__ wp, float* __restrict__ qkvb) {
  int i = blockIdx.x * 256 + threadIdx.x;
  if (i < 110592) wq[i] = f2bf(qkv_w[i]);
  else if (i < 147456) wp[i - 110592] = f2bf(proj_w[i - 110592]);
  else if (i < 148032) {
    int j = i - 147456;
    qkvb[j] = (j < 192) ? q_bias[j] : ((j < 384) ? 0.f : v_bias[j - 384]);
  }
}

// ---------------- k1: CPB MLP table (225 x 8) ----------------
__global__ void k_table(const float* __restrict__ w1, const float* __restrict__ b1,
                        const float* __restrict__ w2, float* __restrict__ table) {
  int row = blockIdx.x;            // 0..224
  int tid = threadIdx.x;
  int a = row / 15, b = row % 15;
  float va = (float)(a - 7) * (8.0f / 7.0f);
  float vb = (float)(b - 7) * (8.0f / 7.0f);
  float c0 = copysignf(log2f(fabsf(va) + 1.0f) * (1.0f / 3.0f), va);
  float c1 = copysignf(log2f(fabsf(vb) + 1.0f) * (1.0f / 3.0f), vb);
  float acc[8];
#pragma unroll
  for (int o = 0; o < 8; ++o) acc[o] = 0.f;
  for (int k = tid; k < 512; k += 256) {
    float h = fmaxf(c0 * w1[k] + c1 * w1[512 + k] + b1[k], 0.f);
#pragma unroll
    for (int o = 0; o < 8; ++o) acc[o] += h * w2[k * 8 + o];
  }
  __shared__ float part[4][8];
  int wave = tid >> 6;
#pragma unroll
  for (int o = 0; o < 8; ++o) {
    float v = acc[o];
    v += __shfl_xor(v, 1, 64);  v += __shfl_xor(v, 2, 64);
    v += __shfl_xor(v, 4, 64);  v += __shfl_xor(v, 8, 64);
    v += __shfl_xor(v, 16, 64); v += __shfl_xor(v, 32, 64);
    acc[o] = v;
  }
  if ((tid & 63) == 0)
#pragma unroll
    for (int o = 0; o < 8; ++o) part[wave][o] = acc[o];
  __syncthreads();
  if (tid < 8)
    table[row * 8 + tid] = part[0][tid] + part[1][tid] + part[2][tid] + part[3][tid];
}

// ---- k2: bias grid, flat = h*4096 + t*64 + g*16 + nt*4 + r;
//      value = bias[h][query t][key s = nt*16 + g*4 + r] ----
__global__ void k_biasfill(const float* __restrict__ table, float* __restrict__ bias3) {
  int p = blockIdx.x * 256 + threadIdx.x;   // 32768 total
  int h = p >> 12, t = (p >> 6) & 63, g = (p >> 4) & 3, u = p & 15;
  int nt = u >> 2, r = u & 3;
  int s = nt * 16 + g * 4 + r;
  int idx = ((t >> 3) - (s >> 3) + 7) * 15 + ((t & 7) - (s & 7) + 7);
  float v = table[idx * 8 + h];
  bias3[p] = 16.0f / (1.0f + __expf(-v));
}

// ------- per-window middle section: q,k,v GEMMs + attention (barrier-free) -------
// Sw = 1728-u16 per-wave scratch, serially reused Hq -> Hk -> Hv(stride 72) -> Pw.
__device__ __forceinline__ void attn_window(
    u16* __restrict__ R0, u16* __restrict__ Sw, float* __restrict__ ikw,
    const u16* __restrict__ wq, const float* __restrict__ qkvb,
    const float* __restrict__ bias3,
    int h, int g, int li, float scaleh,
    const bf16x8* qw0, const bf16x8* qw1) {
  bf16x8 z8 = {0, 0, 0, 0, 0, 0, 0, 0};
  f32x4 zf = {0.f, 0.f, 0.f, 0.f};
  float iqr[4];
  bf16x8 qf[4], kf[4];

  // ---- q GEMM + fused norm -> Hq(=Sw) ----
  {
    f32x4 cb0 = *(const f32x4*)(qkvb + h * 24 + g * 4);
    f32x4 cb1 = *(const f32x4*)(qkvb + h * 24 + 16 + g * 4);   // g>=2 junk, masked
#pragma unroll
    for (int tb = 0; tb < 4; ++tb) {
      int t = tb * 16 + li;
      bf16x8 xf[6];
#pragma unroll
      for (int ks = 0; ks < 6; ++ks)
        xf[ks] = *(const bf16x8*)&R0[t * 200 + ks * 32 + g * 8];
      f32x4 a0 = zf, a1 = zf;
      __builtin_amdgcn_s_setprio(1);
#pragma unroll
      for (int ks = 0; ks < 6; ++ks) {
        a0 = __builtin_amdgcn_mfma_f32_16x16x32_bf16(qw0[ks], xf[ks], a0, 0, 0, 0);
        a1 = __builtin_amdgcn_mfma_f32_16x16x32_bf16(qw1[ks], xf[ks], a1, 0, 0, 0);
      }
      __builtin_amdgcn_s_setprio(0);
      float p = 0.f;
#pragma unroll
      for (int r = 0; r < 4; ++r) { a0[r] += cb0[r]; p += a0[r] * a0[r]; }
      if (g < 2) {
#pragma unroll
        for (int r = 0; r < 4; ++r) { a1[r] += cb1[r]; p += a1[r] * a1[r]; }
      }
      p += __shfl_xor(p, 16, 64);
      p += __shfl_xor(p, 32, 64);
      iqr[tb] = __builtin_amdgcn_rsqf(fmaxf(p, 1e-24f)) * scaleh;
      uint2 pk;
      pk.x = pkbf(a0[0], a0[1]);
      pk.y = pkbf(a0[2], a0[3]);
      *(uint2*)&Sw[t * 24 + g * 4] = pk;
      if (g < 2) {
        pk.x = pkbf(a1[0], a1[1]);
        pk.y = pkbf(a1[2], a1[3]);
        *(uint2*)&Sw[t * 24 + 16 + g * 4] = pk;
      }
    }
  }

  // k-weight loads issued BEFORE the qf hoist so they overlap it
  bf16x8 kw0[6], kw1[6];
  {
    const u16* wr0 = wq + (size_t)(192 + h * 24 + li) * 192 + g * 8;
    const u16* wr1 = wq + (size_t)(192 + h * 24 + 16 + (li & 7)) * 192 + g * 8;
#pragma unroll
    for (int ks = 0; ks < 6; ++ks) {
      kw0[ks] = *(const bf16x8*)(wr0 + ks * 32);
      kw1[ks] = *(const bf16x8*)(wr1 + ks * 32);
    }
  }
  // hoist q fragments (same-wave LDS, in-order); Hq dead after
#pragma unroll
  for (int tb = 0; tb < 4; ++tb)
    qf[tb] = (g < 3) ? *(const bf16x8*)&Sw[(tb * 16 + li) * 24 + g * 8] : z8;

  // ---- k GEMM + norms -> Hk(=Sw) ----
  {
    f32x4 cb0 = *(const f32x4*)(qkvb + 192 + h * 24 + g * 4);
    f32x4 cb1 = *(const f32x4*)(qkvb + 192 + h * 24 + 16 + g * 4);
#pragma unroll
    for (int nt = 0; nt < 4; ++nt) {
      int t = nt * 16 + li;
      bf16x8 xf[6];
#pragma unroll
      for (int ks = 0; ks < 6; ++ks)
        xf[ks] = *(const bf16x8*)&R0[t * 200 + ks * 32 + g * 8];
      f32x4 a0 = zf, a1 = zf;
      __builtin_amdgcn_s_setprio(1);
#pragma unroll
      for (int ks = 0; ks < 6; ++ks) {
        a0 = __builtin_amdgcn_mfma_f32_16x16x32_bf16(kw0[ks], xf[ks], a0, 0, 0, 0);
        a1 = __builtin_amdgcn_mfma_f32_16x16x32_bf16(kw1[ks], xf[ks], a1, 0, 0, 0);
      }
      __builtin_amdgcn_s_setprio(0);
      float p = 0.f;
#pragma unroll
      for (int r = 0; r < 4; ++r) { a0[r] += cb0[r]; p += a0[r] * a0[r]; }
      if (g < 2) {
#pragma unroll
        for (int r = 0; r < 4; ++r) { a1[r] += cb1[r]; p += a1[r] * a1[r]; }
      }
      p += __shfl_xor(p, 16, 64);
      p += __shfl_xor(p, 32, 64);
      float ik = __builtin_amdgcn_rsqf(fmaxf(p, 1e-24f));
      if (g == 0) ikw[t] = ik;
      uint2 pk;
      pk.x = pkbf(a0[0], a0[1]);
      pk.y = pkbf(a0[2], a0[3]);
      *(uint2*)&Sw[t * 24 + g * 4] = pk;
      if (g < 2) {
        pk.x = pkbf(a1[0], a1[1]);
        pk.y = pkbf(a1[2], a1[3]);
        *(uint2*)&Sw[t * 24 + 16 + g * 4] = pk;
      }
    }
  }

  // v-weight loads issued early (independent of Hk)
  bf16x8 vw0[6], vw1[6];
  {
    const u16* wr0 = wq + (size_t)(384 + h * 24 + li) * 192 + g * 8;
    const u16* wr1 = wq + (size_t)(384 + h * 24 + 16 + (li & 7)) * 192 + g * 8;
#pragma unroll
    for (int ks = 0; ks < 6; ++ks) {
      vw0[ks] = *(const bf16x8*)(wr0 + ks * 32);
      vw1[ks] = *(const bf16x8*)(wr1 + ks * 32);
    }
  }
  // hoist k fragments to regs; Hk dead after
#pragma unroll
  for (int nt = 0; nt < 4; ++nt)
    kf[nt] = (g < 3) ? *(const bf16x8*)&Sw[(nt * 16 + li) * 24 + g * 8] : z8;

  // ---- v GEMM -> Hv(=Sw), stride 72 ----
  {
    float vb0 = qkvb[384 + h * 24 + li];
    float vb1 = qkvb[384 + h * 24 + 16 + (li & 7)];
#pragma unroll
    for (int tb = 0; tb < 4; ++tb) {
      int t = tb * 16 + li;
      bf16x8 xf[6];
#pragma unroll
      for (int ks = 0; ks < 6; ++ks)
        xf[ks] = *(const bf16x8*)&R0[t * 200 + ks * 32 + g * 8];
      f32x4 a0 = zf, a1 = zf;
      __builtin_amdgcn_s_setprio(1);
#pragma unroll
      for (int ks = 0; ks < 6; ++ks) {
        a0 = __builtin_amdgcn_mfma_f32_16x16x32_bf16(xf[ks], vw0[ks], a0, 0, 0, 0);
        a1 = __builtin_amdgcn_mfma_f32_16x16x32_bf16(xf[ks], vw1[ks], a1, 0, 0, 0);
      }
      __builtin_amdgcn_s_setprio(0);
      uint2 pk;
      pk.x = pkbf(a0[0] + vb0, a0[1] + vb0);
      pk.y = pkbf(a0[2] + vb0, a0[3] + vb0);
      *(uint2*)&Sw[li * 72 + tb * 16 + g * 4] = pk;
      if (li < 8) {
        pk.x = pkbf(a1[0] + vb1, a1[1] + vb1);
        pk.y = pkbf(a1[2] + vb1, a1[3] + vb1);
        *(uint2*)&Sw[(16 + li) * 72 + tb * 16 + g * 4] = pk;
      }
    }
  }
  // hoist V^T fragments; Hv dead after -> Pw reuses Sw
  bf16x8 vf0[2], vf1[2];
#pragma unroll
  for (int ks = 0; ks < 2; ++ks) {
    vf0[ks] = *(const bf16x8*)&Sw[li * 72 + ks * 32 + g * 8];
    vf1[ks] = (li < 8) ? *(const bf16x8*)&Sw[(16 + li) * 72 + ks * 32 + g * 8] : z8;
  }

  // ---- attention: software-pipelined P bounce (single buffer) ----
  auto compute_s = [&](int tb, uint2* pp) -> float {
    f32x4 bxl[4];
    const float* bp = bias3 + ((h * 64 + tb * 16 + li) << 6) + (g << 4);
#pragma unroll
    for (int nt = 0; nt < 4; ++nt) bxl[nt] = *(const f32x4*)(bp + (nt << 2));
    f32x4 s4[4];
    __builtin_amdgcn_s_setprio(1);
#pragma unroll
    for (int nt = 0; nt < 4; ++nt)
      s4[nt] = __builtin_amdgcn_mfma_f32_16x16x32_bf16(kf[nt], qf[tb], zf, 0, 0, 0);
    __builtin_amdgcn_s_setprio(0);
    float iq = iqr[tb];
#pragma unroll
    for (int nt = 0; nt < 4; ++nt) {
      f32x4 ik4 = *(const f32x4*)&ikw[nt * 16 + g * 4];
#pragma unroll
      for (int r = 0; r < 4; ++r)
        s4[nt][r] = s4[nt][r] * iq * ik4[r] + bxl[nt][r];
    }
    float m = s4[0][0];
#pragma unroll
    for (int nt = 0; nt < 4; ++nt)
#pragma unroll
      for (int r = 0; r < 4; ++r) m = fmaxf(m, s4[nt][r]);
    m = fmaxf(m, __shfl_xor(m, 16, 64));
    m = fmaxf(m, __shfl_xor(m, 32, 64));
    float sum = 0.f;
#pragma unroll
    for (int nt = 0; nt < 4; ++nt)
#pragma unroll
      for (int r = 0; r < 4; ++r) { float e = __expf(s4[nt][r] - m); s4[nt][r] = e; sum += e; }
    sum += __shfl_xor(sum, 16, 64);
    sum += __shfl_xor(sum, 32, 64);
#pragma unroll
    for (int nt = 0; nt < 4; ++nt) {
      pp[nt].x = pkbf(s4[nt][0], s4[nt][1]);
      pp[nt].y = pkbf(s4[nt][2], s4[nt][3]);
    }
    return __builtin_amdgcn_rcpf(sum);
  };

  uint2 pc[4];
  float isc = compute_s(0, pc);
#pragma unroll
  for (int nt = 0; nt < 4; ++nt)
    *(uint2*)&Sw[li * 72 + nt * 16 + g * 4] = pc[nt];

#pragma unroll
  for (int tb = 0; tb < 4; ++tb) {
    uint2 pn[4];
    float isn = 0.f;
    if (tb < 3) isn = compute_s(tb + 1, pn);   // fills the P store->read gap
    // PV: O^T = V^T . P^T (read tb's P, stored last iteration)
    f32x4 o0 = zf, o1 = zf;
    __builtin_amdgcn_s_setprio(1);
#pragma unroll
    for (int ks = 0; ks < 2; ++ks) {
      bf16x8 pf = *(const bf16x8*)&Sw[li * 72 + ks * 32 + g * 8];
      o0 = __builtin_amdgcn_mfma_f32_16x16x32_bf16(vf0[ks], pf, o0, 0, 0, 0);
      o1 = __builtin_amdgcn_mfma_f32_16x16x32_bf16(vf1[ks], pf, o1, 0, 0, 0);
    }
    __builtin_amdgcn_s_setprio(0);
    int t = tb * 16 + li;
    {
      uint2 pk;
      pk.x = pkbf(o0[0] * isc, o0[1] * isc);
      pk.y = pkbf(o0[2] * isc, o0[3] * isc);
      *(uint2*)&R0[t * 200 + h * 24 + g * 4] = pk;
    }
    if (g < 2) {
      uint2 pk;
      pk.x = pkbf(o1[0] * isc, o1[1] * isc);
      pk.y = pkbf(o1[2] * isc, o1[3] * isc);
      *(uint2*)&R0[t * 200 + h * 24 + 16 + g * 4] = pk;
    }
    if (tb < 3) {                               // store next P (after this read)
#pragma unroll
      for (int nt = 0; nt < 4; ++nt)
        *(uint2*)&Sw[li * 72 + nt * 16 + g * 4] = pn[nt];
      isc = isn;
    }
  }
}

// ------- main fused kernel: 2 windows/block, 8 waves, 2 blocks/CU -------
__global__ __launch_bounds__(512, 2)
void k_main(const float* __restrict__ x,
            const float* __restrict__ ls, const float* __restrict__ proj_b,
            const u16* __restrict__ wq, const u16* __restrict__ wp,
            const float* __restrict__ qkvb, const float* __restrict__ bias3,
            float* __restrict__ out) {
  __shared__ u16 smem[40448];                 // 80,896 B
  u16* R0A = smem;                            // [64][200]: xA, later aoA
  u16* R0B = smem + 12800;                    // [64][200]: xB, later aoB
  u16* Sc  = smem + 25600;                    // 8 x 1728 u16 per-wave scratch
  float* ikwb = (float*)(smem + 39424);       // 8 x 64 f32

  int tid  = threadIdx.x;
  int h = tid >> 6, lane = tid & 63, g = lane >> 4, li = lane & 15;
  int tt = h & 3, half = h >> 2;              // proj-phase roles
  int bid = blockIdx.x;                       // 2048 blocks
  int b = bid >> 9, rem = bid & 511, wy = rem >> 4, wxp = rem & 15;
  const float* xb = x + (size_t)b * C_ * HW_;
  int baseA = (wy * 8) * 256 + wxp * 16;      // window pair: 16 consecutive px
  f32x4 zf = {0.f, 0.f, 0.f, 0.f};

  u16* Sw = Sc + h * 1728;
  float* ikw = ikwb + h * 64;
  float scaleh = __expf(fminf(ls[h], 4.6051702f));

  // prefetch window-A q-weights (hidden under P1's HBM loads)
  bf16x8 qwA0[6], qwA1[6];
  {
    const u16* wr0 = wq + (size_t)(h * 24 + li) * 192 + g * 8;
    const u16* wr1 = wq + (size_t)(h * 24 + 16 + (li & 7)) * 192 + g * 8;
#pragma unroll
    for (int ks = 0; ks < 6; ++ks) {
      qwA0[ks] = *(const bf16x8*)(wr0 + ks * 32);
      qwA1[ks] = *(const bf16x8*)(wr1 + ks * 32);
    }
  }

  // ---- P1: stage both windows; 32 thr/channel -> full 64B lines ----
#pragma unroll
  for (int it = 0; it < 12; ++it) {
    int i4 = tid + it * 512;                  // 6144 tasks
    int c = i4 >> 5, r5 = i4 & 31;
    int ty = r5 >> 2, jq = (r5 & 3) * 4;      // jq = 0,4,8,12 across the pair
    float4 v = *(const float4*)(xb + c * HW_ + baseA + ty * 256 + jq);
    u16* Rw = (jq < 8) ? R0A : R0B;
    int t0 = ty * 8 + (jq & 7);
    unsigned p01 = pkbf(v.x, v.y), p23 = pkbf(v.z, v.w);
    Rw[(t0 + 0) * 200 + c] = (u16)p01;
    Rw[(t0 + 1) * 200 + c] = (u16)(p01 >> 16);
    Rw[(t0 + 2) * 200 + c] = (u16)p23;
    Rw[(t0 + 3) * 200 + c] = (u16)(p23 >> 16);
  }
  __syncthreads();                            // B1

  // ---- window A middle (cold weight fetches) ----
  attn_window(R0A, Sw, ikw, wq, qkvb, bias3, h, g, li, scaleh, qwA0, qwA1);

  // ---- window B middle (all weight/bias reloads are L1/L2-hot) ----
  bf16x8 qwB0[6], qwB1[6];
  {
    const u16* wr0 = wq + (size_t)(h * 24 + li) * 192 + g * 8;
    const u16* wr1 = wq + (size_t)(h * 24 + 16 + (li & 7)) * 192 + g * 8;
#pragma unroll
    for (int ks = 0; ks < 6; ++ks) {
      qwB0[ks] = *(const bf16x8*)(wr0 + ks * 32);
      qwB1[ks] = *(const bf16x8*)(wr1 + ks * 32);
    }
  }
  attn_window(R0B, Sw, ikw, wq, qkvb, bias3, h, g, li, scaleh, qwB0, qwB1);
  __syncthreads();                            // B2 (aoA, aoB complete)

  // ---- proj: load af for both windows, then shared-weight GEMM ----
  bf16x8 afA[6], afB[6];
#pragma unroll
  for (int ks = 0; ks < 6; ++ks) {
    afA[ks] = *(const bf16x8*)&R0A[(tt * 16 + li) * 200 + ks * 32 + g * 8];
    afB[ks] = *(const bf16x8*)&R0B[(tt * 16 + li) * 200 + ks * 32 + g * 8];
  }
  __syncthreads();                            // B3 (af in regs; R0/Sc reusable)

  u16* obufA = Sc;                            // [192][68] over Sc (26112 <= 27648)
  u16* obufB = smem;                          // [192][68] over R0A/R0B
#pragma unroll
  for (int it = 0; it < 6; ++it) {
    int ct = half * 96 + it * 16;
    const u16* wr = wp + (size_t)(ct + li) * 192 + g * 8;
    bf16x8 w6[6];
#pragma unroll
    for (int ks = 0; ks < 6; ++ks) w6[ks] = *(const bf16x8*)(wr + ks * 32);
    f32x4 aA0 = zf, aA1 = zf, aB0 = zf, aB1 = zf;
    __builtin_amdgcn_s_setprio(1);
#pragma unroll
    for (int ks = 0; ks < 3; ++ks) {
      aA0 = __builtin_amdgcn_mfma_f32_16x16x32_bf16(afA[ks], w6[ks], aA0, 0, 0, 0);
      aA1 = __builtin_amdgcn_mfma_f32_16x16x32_bf16(afA[ks + 3], w6[ks + 3], aA1, 0, 0, 0);
      aB0 = __builtin_amdgcn_mfma_f32_16x16x32_bf16(afB[ks], w6[ks], aB0, 0, 0, 0);
      aB1 = __builtin_amdgcn_mfma_f32_16x16x32_bf16(afB[ks + 3], w6[ks + 3], aB1, 0, 0, 0);
    }
    __builtin_amdgcn_s_setprio(0);
    float pb = proj_b[ct + li];
    uint2 pk;
    pk.x = pkbf(aA0[0] + aA1[0] + pb, aA0[1] + aA1[1] + pb);
    pk.y = pkbf(aA0[2] + aA1[2] + pb, aA0[3] + aA1[3] + pb);
    *(uint2*)&obufA[(ct + li) * 68 + tt * 16 + g * 4] = pk;
    pk.x = pkbf(aB0[0] + aB1[0] + pb, aB0[1] + aB1[1] + pb);
    pk.y = pkbf(aB0[2] + aB1[2] + pb, aB0[3] + aB1[3] + pb);
    *(uint2*)&obufB[(ct + li) * 68 + tt * 16 + g * 4] = pk;
  }
  __syncthreads();                            // B4

  // ---- P6: residual + store, pair-joint (full 64B lines), 2 batches of 6 ----
  float* ob = out + (size_t)b * C_ * HW_;
#pragma unroll
  for (int bt = 0; bt < 2; ++bt) {
    float4 xv[6];
    uint2 ov[6];
#pragma unroll
    for (int it = 0; it < 6; ++it) {
      int i4 = tid + (bt * 6 + it) * 512;
      int c = i4 >> 5, r5 = i4 & 31;
      int ty = r5 >> 2, jq = (r5 & 3) * 4;
      xv[it] = *(const float4*)(xb + c * HW_ + baseA + ty * 256 + jq);
    }
#pragma unroll
    for (int it = 0; it < 6; ++it) {
      int i4 = tid + (bt * 6 + it) * 512;
      int c = i4 >> 5, r5 = i4 & 31;
      int ty = r5 >> 2, jq = (r5 & 3) * 4;
      const u16* obw = (jq < 8) ? obufA : obufB;
      ov[it] = *(const uint2*)&obw[c * 68 + ty * 8 + (jq & 7)];
    }
#pragma unroll
    for (int it = 0; it < 6; ++it) {
      int i4 = tid + (bt * 6 + it) * 512;
      int c = i4 >> 5, r5 = i4 & 31;
      int ty = r5 >> 2, jq = (r5 & 3) * 4;
      float4 r;
      r.x = xv[it].x + bf2f((u16)(ov[it].x & 0xFFFFu));
      r.y = xv[it].y + bf2f((u16)(ov[it].x >> 16));
      r.z = xv[it].z + bf2f((u16)(ov[it].y & 0xFFFFu));
      r.w = xv[it].w + bf2f((u16)(ov[it].y >> 16));
      *(float4*)(ob + c * HW_ + baseA + ty * 256 + jq) = r;
    }
  }
}

// ---------------- launcher ----------------
extern "C" void kernel_launch(void* const* d_in, const int* in_sizes, int n_in,
                              void* d_out, int out_size, void* d_ws, size_t ws_size,
                              hipStream_t stream) {
  const float* x      = (const float*)d_in[0];
  const float* qkv_w  = (const float*)d_in[2];
  const float* q_bias = (const float*)d_in[3];
  const float* v_bias = (const float*)d_in[4];
  const float* ls     = (const float*)d_in[5];
  const float* w1     = (const float*)d_in[6];
  const float* b1     = (const float*)d_in[7];
  const float* w2     = (const float*)d_in[8];
  const float* proj_w = (const float*)d_in[9];
  const float* proj_b = (const float*)d_in[10];

  u16*   wq    = (u16*)d_ws;                               // 110592 bf16
  u16*   wpv   = wq + 110592;                              // 36864 bf16 -> byte 294912
  float* qkvb  = (float*)((char*)d_ws + 294912);           // 576 f32   -> 297216
  float* bias3 = (float*)((char*)d_ws + 297216);           // 32768 f32 -> 428288
  float* table = (float*)((char*)d_ws + 428288);           // 1800 f32
  float* out   = (float*)d_out;

  hipLaunchKernelGGL(k_convert, dim3(579), dim3(256), 0, stream,
                     qkv_w, proj_w, q_bias, v_bias, wq, wpv, qkvb);
  hipLaunchKernelGGL(k_table, dim3(225), dim3(256), 0, stream, w1, b1, w2, table);
  hipLaunchKernelGGL(k_biasfill, dim3(128), dim3(256), 0, stream, table, bias3);
  hipLaunchKernelGGL(k_main, dim3(2048), dim3(512), 0, stream,
                     x, ls, proj_b, wq, wpv, qkvb, bias3, out);
}